// Round 1
// baseline (559.477 us; speedup 1.0000x reference)
//
#include <hip/hip_runtime.h>
#include <math.h>

#define D 2048
#define S_LEN 4096
#define NB 4
#define NTOK (NB * S_LEN)  // 16384

__device__ __forceinline__ float gelu_tanh(float v) {
    const float c = 0.7978845608028654f;
    float t = tanhf(c * (v + 0.044715f * v * v * v));
    return 0.5f * v * (1.0f + t);
}

// ---------------- K1: u[t][r] = rsqrt(mean(x^2)+eps) * sum_d x[d]*nw[d]*V[d][r]
// one wave handles 4 tokens (V rows shared in regs across the 4 tokens)
__global__ __launch_bounds__(256) void k1_u_kernel(
        const float* __restrict__ x, const float* __restrict__ nw,
        const float* __restrict__ V, float* __restrict__ u)
{
    const int gwave = (blockIdx.x * 256 + threadIdx.x) >> 6;
    const int lane  = threadIdx.x & 63;
    const int t0 = gwave * 4;
    const float4* V4 = reinterpret_cast<const float4*>(V);

    float ss[4] = {0.f, 0.f, 0.f, 0.f};
    float uv[4][4] = {};

    #pragma unroll
    for (int j = 0; j < 8; ++j) {
        const int d0 = j * 256 + lane * 4;
        const float4 nw4 = *reinterpret_cast<const float4*>(nw + d0);
        float4 vr[4];
        #pragma unroll
        for (int i = 0; i < 4; ++i) vr[i] = V4[d0 + i];
        #pragma unroll
        for (int tk = 0; tk < 4; ++tk) {
            const float4 xv = *reinterpret_cast<const float4*>(x + (size_t)(t0 + tk) * D + d0);
            ss[tk] += xv.x*xv.x + xv.y*xv.y + xv.z*xv.z + xv.w*xv.w;
            const float z0 = xv.x*nw4.x, z1 = xv.y*nw4.y, z2 = xv.z*nw4.z, z3 = xv.w*nw4.w;
            uv[tk][0] += z0*vr[0].x + z1*vr[1].x + z2*vr[2].x + z3*vr[3].x;
            uv[tk][1] += z0*vr[0].y + z1*vr[1].y + z2*vr[2].y + z3*vr[3].y;
            uv[tk][2] += z0*vr[0].z + z1*vr[1].z + z2*vr[2].z + z3*vr[3].z;
            uv[tk][3] += z0*vr[0].w + z1*vr[1].w + z2*vr[2].w + z3*vr[3].w;
        }
    }
    #pragma unroll
    for (int m = 1; m < 64; m <<= 1) {
        #pragma unroll
        for (int tk = 0; tk < 4; ++tk) {
            ss[tk] += __shfl_xor(ss[tk], m);
            #pragma unroll
            for (int r = 0; r < 4; ++r) uv[tk][r] += __shfl_xor(uv[tk][r], m);
        }
    }
    if (lane < 16) {
        float ssv = ss[0], uvv = uv[0][0];
        #pragma unroll
        for (int tk = 0; tk < 4; ++tk)
            #pragma unroll
            for (int r = 0; r < 4; ++r)
                if (lane == tk * 4 + r) { ssv = ss[tk]; uvv = uv[tk][r]; }
        const float rstd = rsqrtf(ssv * (1.0f / 2048.0f) + 1e-6f);
        u[(size_t)t0 * 4 + lane] = rstd * uvv;  // contiguous 64B store
    }
}

// ---------------- K2: chunked scan  h_t = a*h_{t-1} + u_t  per (b, r) series
__global__ __launch_bounds__(256) void k2_scan_kernel(
        const float* __restrict__ u, const float* __restrict__ a_logit,
        float* __restrict__ hs)
{
    __shared__ float lds[256];
    const int b = blockIdx.x >> 2;
    const int r = blockIdx.x & 3;
    const int i = threadIdx.x;
    const float a = 1.0f / (1.0f + expf(-a_logit[r]));
    const float* up = u  + (size_t)b * S_LEN * 4 + r;
    float*       hp = hs + (size_t)b * S_LEN * 4 + r;

    float ul[16];
    float h = 0.f;
    const int s0 = i * 16;
    #pragma unroll
    for (int k = 0; k < 16; ++k) { ul[k] = up[(size_t)(s0 + k) * 4]; h = a * h + ul[k]; }

    const float a2 = a*a, a4 = a2*a2, a8 = a4*a4;
    float m = a8 * a8;  // a^16
    float run = h;
    lds[i] = run;
    for (int off = 1; off < 256; off <<= 1) {
        __syncthreads();
        const float v = (i >= off) ? lds[i - off] : 0.f;
        __syncthreads();
        run += m * v;
        lds[i] = run;
        m *= m;
    }
    __syncthreads();
    float hh = (i == 0) ? 0.f : lds[i - 1];
    #pragma unroll
    for (int k = 0; k < 16; ++k) { hh = a * hh + ul[k]; hp[(size_t)(s0 + k) * 4] = hh; }
}

// ---------------- K3: fused  x2 = x + hs*U^T ; rms2 ; t = gelu(n2@W1) ; out = x2 + t@W2
// one wave handles 4 tokens; x2 recomputed in epilogue pass (x is L2/L3-hot)
__global__ __launch_bounds__(256) void k3_fused_kernel(
        const float* __restrict__ x, const float* __restrict__ nw,
        const float* __restrict__ U, const float* __restrict__ hs,
        const float* __restrict__ W1, const float* __restrict__ W2,
        float* __restrict__ out)
{
    __shared__ float reds[4][4][20];
    __shared__ float tvs[4][64];
    const int w = threadIdx.x >> 6;
    const int lane = threadIdx.x & 63;
    const int gwave = blockIdx.x * 4 + w;
    const int t0 = gwave * 4;
    const float4* U4  = reinterpret_cast<const float4*>(U);
    const float4* hs4 = reinterpret_cast<const float4*>(hs);
    float4 hv[4];
    #pragma unroll
    for (int tk = 0; tk < 4; ++tk) hv[tk] = hs4[t0 + tk];

    float ss[4] = {0.f, 0.f, 0.f, 0.f};
    float pf[4][16] = {};

    // phase A: ss (rms2) and pf (n2 @ W1) accumulation
    #pragma unroll
    for (int j = 0; j < 8; ++j) {
        const int d0 = j * 256 + lane * 4;
        const float4 nw4 = *reinterpret_cast<const float4*>(nw + d0);
        float4 ur[4];
        #pragma unroll
        for (int i = 0; i < 4; ++i) ur[i] = U4[d0 + i];
        float4 w1r[4][4];
        #pragma unroll
        for (int i = 0; i < 4; ++i)
            #pragma unroll
            for (int c = 0; c < 4; ++c)
                w1r[i][c] = *reinterpret_cast<const float4*>(W1 + (size_t)(d0 + i) * 16 + c * 4);
        #pragma unroll
        for (int tk = 0; tk < 4; ++tk) {
            const float4 xv = *reinterpret_cast<const float4*>(x + (size_t)(t0 + tk) * D + d0);
            const float y0 = hv[tk].x*ur[0].x + hv[tk].y*ur[0].y + hv[tk].z*ur[0].z + hv[tk].w*ur[0].w;
            const float y1 = hv[tk].x*ur[1].x + hv[tk].y*ur[1].y + hv[tk].z*ur[1].z + hv[tk].w*ur[1].w;
            const float y2 = hv[tk].x*ur[2].x + hv[tk].y*ur[2].y + hv[tk].z*ur[2].z + hv[tk].w*ur[2].w;
            const float y3 = hv[tk].x*ur[3].x + hv[tk].y*ur[3].y + hv[tk].z*ur[3].z + hv[tk].w*ur[3].w;
            const float x20 = xv.x + y0, x21 = xv.y + y1, x22 = xv.z + y2, x23 = xv.w + y3;
            ss[tk] += x20*x20 + x21*x21 + x22*x22 + x23*x23;
            const float z0 = x20*nw4.x, z1 = x21*nw4.y, z2 = x22*nw4.z, z3 = x23*nw4.w;
            #pragma unroll
            for (int c = 0; c < 4; ++c) {
                pf[tk][c*4+0] += z0*w1r[0][c].x + z1*w1r[1][c].x + z2*w1r[2][c].x + z3*w1r[3][c].x;
                pf[tk][c*4+1] += z0*w1r[0][c].y + z1*w1r[1][c].y + z2*w1r[2][c].y + z3*w1r[3][c].y;
                pf[tk][c*4+2] += z0*w1r[0][c].z + z1*w1r[1][c].z + z2*w1r[2][c].z + z3*w1r[3][c].z;
                pf[tk][c*4+3] += z0*w1r[0][c].w + z1*w1r[1][c].w + z2*w1r[2][c].w + z3*w1r[3][c].w;
            }
        }
    }

    // in-wave butterfly reduction (all lanes end with identical full sums)
    #pragma unroll
    for (int m = 1; m < 64; m <<= 1) {
        #pragma unroll
        for (int tk = 0; tk < 4; ++tk) {
            ss[tk] += __shfl_xor(ss[tk], m);
            #pragma unroll
            for (int f = 0; f < 16; ++f) pf[tk][f] += __shfl_xor(pf[tk][f], m);
        }
    }
    if (lane == 0) {
        #pragma unroll
        for (int tk = 0; tk < 4; ++tk) {
            reds[w][tk][16] = ss[tk];
            #pragma unroll
            for (int f = 0; f < 16; ++f) reds[w][tk][f] = pf[tk][f];
        }
    }
    __syncthreads();
    {
        const int mytk = lane >> 4, myf = lane & 15;  // 64 lanes = 4 tokens x 16 f: one gelu each
        const float rstd = rsqrtf(reds[w][mytk][16] * (1.0f / 2048.0f) + 1e-6f);
        tvs[w][lane] = gelu_tanh(rstd * reds[w][mytk][myf]);
    }
    __syncthreads();
    float tvv[4][16];
    #pragma unroll
    for (int tk = 0; tk < 4; ++tk)
        #pragma unroll
        for (int f = 0; f < 16; ++f) tvv[tk][f] = tvs[w][tk * 16 + f];

    // phase C: out = x2 + t @ W2  (x2 recomputed; x row is L2-hot from phase A)
    #pragma unroll
    for (int j = 0; j < 8; ++j) {
        const int d0 = j * 256 + lane * 4;
        float4 ur[4];
        #pragma unroll
        for (int i = 0; i < 4; ++i) ur[i] = U4[d0 + i];
        float4 acc[4];
        #pragma unroll
        for (int tk = 0; tk < 4; ++tk) {
            const float4 xv = *reinterpret_cast<const float4*>(x + (size_t)(t0 + tk) * D + d0);
            acc[tk].x = xv.x + hv[tk].x*ur[0].x + hv[tk].y*ur[0].y + hv[tk].z*ur[0].z + hv[tk].w*ur[0].w;
            acc[tk].y = xv.y + hv[tk].x*ur[1].x + hv[tk].y*ur[1].y + hv[tk].z*ur[1].z + hv[tk].w*ur[1].w;
            acc[tk].z = xv.z + hv[tk].x*ur[2].x + hv[tk].y*ur[2].y + hv[tk].z*ur[2].z + hv[tk].w*ur[2].w;
            acc[tk].w = xv.w + hv[tk].x*ur[3].x + hv[tk].y*ur[3].y + hv[tk].z*ur[3].z + hv[tk].w*ur[3].w;
        }
        #pragma unroll
        for (int f = 0; f < 16; ++f) {
            const float4 w2v = *reinterpret_cast<const float4*>(W2 + (size_t)f * D + d0);
            #pragma unroll
            for (int tk = 0; tk < 4; ++tk) {
                acc[tk].x += tvv[tk][f] * w2v.x;
                acc[tk].y += tvv[tk][f] * w2v.y;
                acc[tk].z += tvv[tk][f] * w2v.z;
                acc[tk].w += tvv[tk][f] * w2v.w;
            }
        }
        #pragma unroll
        for (int tk = 0; tk < 4; ++tk)
            *reinterpret_cast<float4*>(out + (size_t)(t0 + tk) * D + d0) = acc[tk];
    }
}

extern "C" void kernel_launch(void* const* d_in, const int* in_sizes, int n_in,
                              void* d_out, int out_size, void* d_ws, size_t ws_size,
                              hipStream_t stream)
{
    (void)in_sizes; (void)n_in; (void)out_size; (void)ws_size;
    const float* x  = (const float*)d_in[0];
    const float* nw = (const float*)d_in[1];
    const float* V  = (const float*)d_in[2];
    const float* U  = (const float*)d_in[3];
    const float* al = (const float*)d_in[4];
    const float* W1 = (const float*)d_in[5];
    const float* W2 = (const float*)d_in[6];
    float* out = (float*)d_out;
    float* u   = (float*)d_ws;                 // [NTOK][4]
    float* hs  = u + (size_t)NTOK * 4;         // [NTOK][4]

    k1_u_kernel  <<<dim3(NTOK / 16), dim3(256), 0, stream>>>(x, nw, V, u);
    k2_scan_kernel<<<dim3(16),        dim3(256), 0, stream>>>(u, al, hs);
    k3_fused_kernel<<<dim3(NTOK / 16), dim3(256), 0, stream>>>(x, nw, U, hs, W1, W2, out);
}